// Round 3
// baseline (307.040 us; speedup 1.0000x reference)
//
#include <hip/hip_runtime.h>
#include <hip/hip_bf16.h>
#include <hip/hip_cooperative_groups.h>

namespace cg = cooperative_groups;

#define BATCH 8
#define SEQ   2048
#define FEATD 128
#define IBLK  32
#define JT    64

typedef __attribute__((ext_vector_type(8))) short short8;
typedef __attribute__((ext_vector_type(4))) float f32x4;

__device__ __forceinline__ unsigned short f2bf(float f) {
  unsigned int u = __float_as_uint(f);
  u += 0x7fffu + ((u >> 16) & 1u);   // round-to-nearest-even
  return (unsigned short)(u >> 16);
}

// ---- phase-2 helper macros (named regs -> static indexing, no scratch) ----
#define LOADN4(JTV, N0, N1, N2, N3) { \
    const float4* p_ = (const float4*)(nbase + (size_t)(JTV) * JT); \
    N0 = p_[0]; N1 = p_[1]; N2 = p_[8]; N3 = p_[9]; }   /* ks0: +0..7, ks1: +32..39 */

#define PROCB(N0, N1, N2, N3, PK0, PK1) { \
    float x_[16] = {N0.x, N0.y, N0.z, N0.w, N1.x, N1.y, N1.z, N1.w, \
                    N2.x, N2.y, N2.z, N2.w, N3.x, N3.y, N3.z, N3.w}; \
    _Pragma("unroll") \
    for (int k_ = 0; k_ < 8; k_++) { \
      float e_ = __expf(x_[k_] * sn); \
      unsigned short h_ = f2bf(e_); \
      PK0[k_] = (short)h_; \
      psum += __uint_as_float(((unsigned int)h_) << 16); \
    } \
    _Pragma("unroll") \
    for (int k_ = 0; k_ < 8; k_++) { \
      float e_ = __expf(x_[8 + k_] * sn); \
      unsigned short h_ = f2bf(e_); \
      PK1[k_] = (short)h_; \
      psum += __uint_as_float(((unsigned int)h_) << 16); \
    } }

#define MFMAB(PK0, PK1, JTV) { \
    const unsigned short* fb_ = fbT + (size_t)(JTV) * JT; \
    _Pragma("unroll") \
    for (int fc = 0; fc < 4; fc++) { \
      short8 b0_ = *(const short8*)(fb_ + (size_t)fc * 16 * SEQ); \
      short8 b1_ = *(const short8*)(fb_ + (size_t)fc * 16 * SEQ + 32); \
      acc[fc] = __builtin_amdgcn_mfma_f32_16x16x32_bf16(PK0, b0_, acc[fc], 0, 0, 0); \
      acc[fc] = __builtin_amdgcn_mfma_f32_16x16x32_bf16(PK1, b1_, acc[fc], 0, 0, 0); \
    } }

__global__ __launch_bounds__(256, 2)
void frame_kernel(const float* __restrict__ feature,
                  const float* __restrict__ noise,
                  float* __restrict__ out,
                  float* __restrict__ stab,
                  unsigned int* __restrict__ gmax,
                  unsigned short* __restrict__ featT) {
  __shared__ float tile[32][132];
  __shared__ float wmax[4];

  int bid = blockIdx.x;
  int t   = threadIdx.x;

  // ================= phase 1: stats + bf16 transpose =================
  {
    int b  = bid >> 6;
    int j0 = (bid & 63) * 32;
    int r  = t >> 3;      // row 0..31
    int seg = t & 7;      // 8 segs x 16 floats

    const float* rp = feature + ((size_t)(b * SEQ + j0 + r)) * FEATD + seg * 16;
    float s = 0.0f, ss = 0.0f;
    #pragma unroll
    for (int k = 0; k < 4; k++) {
      float4 v = ((const float4*)rp)[k];
      tile[r][seg * 16 + k * 4 + 0] = v.x;
      tile[r][seg * 16 + k * 4 + 1] = v.y;
      tile[r][seg * 16 + k * 4 + 2] = v.z;
      tile[r][seg * 16 + k * 4 + 3] = v.w;
      s  += v.x + v.y + v.z + v.w;
      ss += v.x * v.x + v.y * v.y + v.z * v.z + v.w * v.w;
    }
    #pragma unroll
    for (int d = 1; d < 8; d <<= 1) {
      s  += __shfl_xor(s, d, 8);
      ss += __shfl_xor(ss, d, 8);
    }
    float st = 0.0f;
    if (seg == 0) {
      float var = (ss - s * s * (1.0f / 128.0f)) * (1.0f / 127.0f);  // ddof=1
      st = 1.0f / (var + 1e-6f);
      stab[(size_t)b * SEQ + j0 + r] = st;
    }
    float m = st;
    #pragma unroll
    for (int d = 1; d < 64; d <<= 1) m = fmaxf(m, __shfl_xor(m, d, 64));
    if ((t & 63) == 0) wmax[t >> 6] = m;
    __syncthreads();
    if (t == 0) {
      float mm = fmaxf(fmaxf(wmax[0], wmax[1]), fmaxf(wmax[2], wmax[3]));
      atomicMax(gmax, __float_as_uint(mm));   // positive floats: uint order == float order
    }
    // transposed bf16 write: thread t -> f = t>>1, j-half = t&1
    int f  = t >> 1;
    int jh = t & 1;
    unsigned short obuf[16];
    #pragma unroll
    for (int jj = 0; jj < 16; jj++) obuf[jj] = f2bf(tile[jh * 16 + jj][f]);
    unsigned short* dst = featT + ((size_t)(b * FEATD + f)) * SEQ + j0 + jh * 16;
    *(uint4*)(dst)     = *(const uint4*)&obuf[0];
    *(uint4*)(dst + 8) = *(const uint4*)&obuf[8];
  }

  cg::this_grid().sync();

  // ================= phase 2: exp + (e @ featT) + normalize; no LDS, no barriers =================
  {
    int b   = bid >> 6;
    int i0  = (bid & 63) * IBLK;
    int wv   = t >> 6;
    int lane = t & 63;
    int l15  = lane & 15;
    int lg   = lane >> 4;
    int wi   = (wv >> 1) * 16;   // i sub-block (0 or 16)
    int wf   = (wv & 1) * 64;    // f sub-block (0 or 64)
    int row  = i0 + wi + l15;

    float gmaxv = __uint_as_float(*gmax);
    float sn = stab[(size_t)b * SEQ + row] / gmaxv;

    const float* nbase = noise + ((size_t)b * SEQ + row) * SEQ + lg * 8;
    const unsigned short* fbT = featT + (size_t)b * FEATD * SEQ + (size_t)(wf + l15) * SEQ + lg * 8;

    f32x4 acc[4];
    #pragma unroll
    for (int k = 0; k < 4; k++) {
      f32x4 z = {0.0f, 0.0f, 0.0f, 0.0f};
      acc[k] = z;
    }
    float psum = 0.0f;

    float4 nA0, nA1, nA2, nA3, nB0, nB1, nB2, nB3;
    short8 pkA0, pkA1, pkB0, pkB1;

    LOADN4(0, nA0, nA1, nA2, nA3);
    for (int jt = 0; jt < SEQ / JT; jt += 2) {
      LOADN4(jt + 1, nB0, nB1, nB2, nB3);
      PROCB(nA0, nA1, nA2, nA3, pkA0, pkA1);
      MFMAB(pkA0, pkA1, jt);
      if (jt + 2 < SEQ / JT) { LOADN4(jt + 2, nA0, nA1, nA2, nA3); }
      PROCB(nB0, nB1, nB2, nB3, pkB0, pkB1);
      MFMAB(pkB0, pkB1, jt + 1);
    }

    // row sums: reduce over the 4 lg-lane groups (each lane covered 16 j per jt)
    psum += __shfl_xor(psum, 16, 64);
    psum += __shfl_xor(psum, 32, 64);
    // every lane now holds rowsum[i0+wi+l15]

    float* orow = out + ((size_t)b * SEQ + i0 + wi) * FEATD + wf;
    #pragma unroll
    for (int v = 0; v < 4; v++) {
      int r = lg * 4 + v;                  // D row = (lane>>4)*4 + reg (m89-verified)
      float rs = __shfl(psum, r, 64);      // lane r (l15=r) holds rowsum[wi+r]
      float rinv = 1.0f / rs;
      #pragma unroll
      for (int fc = 0; fc < 4; fc++) {
        orow[(size_t)r * FEATD + fc * 16 + l15] = acc[fc][v] * rinv;
      }
    }
  }
}

extern "C" void kernel_launch(void* const* d_in, const int* in_sizes, int n_in,
                              void* d_out, int out_size, void* d_ws, size_t ws_size,
                              hipStream_t stream) {
  const float* feature = (const float*)d_in[0];
  const float* noise   = (const float*)d_in[1];
  float* out = (float*)d_out;

  // ws layout: [0,64K) stab f32[16384]; [64K] gmax u32; [128K, 128K+8.4MB) featT bf16
  float* stab           = (float*)d_ws;
  unsigned int* gmax    = (unsigned int*)((char*)d_ws + (64 << 10));
  unsigned short* featT = (unsigned short*)((char*)d_ws + (128 << 10));

  hipMemsetAsync(gmax, 0, sizeof(unsigned int), stream);

  void* args[] = { (void*)&feature, (void*)&noise, (void*)&out,
                   (void*)&stab, (void*)&gmax, (void*)&featT };
  hipLaunchCooperativeKernel((void*)frame_kernel, dim3(BATCH * SEQ / IBLK), dim3(256),
                             args, 0, stream);
}

// Round 4
// 228.610 us; speedup vs baseline: 1.3431x; 1.3431x over previous
//
#include <hip/hip_runtime.h>
#include <hip/hip_bf16.h>

#define BATCH 8
#define SEQ   2048
#define FEATD 128
#define IBLK  32
#define JT    64
#define KSPLIT 2
#define KLEN  (SEQ / KSPLIT)   // 1024
#define NJT   (KLEN / JT)      // 16

typedef __attribute__((ext_vector_type(8))) short short8;
typedef __attribute__((ext_vector_type(4))) float f32x4;

__device__ __forceinline__ unsigned short f2bf(float f) {
  unsigned int u = __float_as_uint(f);
  u += 0x7fffu + ((u >> 16) & 1u);   // round-to-nearest-even
  return (unsigned short)(u >> 16);
}

__device__ __forceinline__ void gll16(const unsigned short* gsrc, unsigned short* lds) {
  __builtin_amdgcn_global_load_lds(
      (const __attribute__((address_space(1))) void*)gsrc,
      (__attribute__((address_space(3))) void*)lds, 16, 0, 0);
}

// ---------------- kernel 1: stats (var->stab, block-reduced max) + bf16 transpose ----------------
__global__ __launch_bounds__(256)
void prep_kernel(const float* __restrict__ feature,
                 float* __restrict__ stab,
                 unsigned int* __restrict__ gmax,
                 unsigned short* __restrict__ featT) {
  __shared__ float tile[32][133];   // pad 133: phase-2 col reads 2-way max
  __shared__ float wmax[4];
  int bid = blockIdx.x;
  int b   = bid >> 6;
  int j0  = (bid & 63) * 32;
  int t   = threadIdx.x;
  int r   = t >> 3;      // row 0..31
  int seg = t & 7;       // 8 segs x 16 floats

  const float* rp = feature + ((size_t)(b * SEQ + j0 + r)) * FEATD + seg * 16;
  float s = 0.0f, ss = 0.0f;
  #pragma unroll
  for (int k = 0; k < 4; k++) {
    float4 v = ((const float4*)rp)[k];
    tile[r][seg * 16 + k * 4 + 0] = v.x;
    tile[r][seg * 16 + k * 4 + 1] = v.y;
    tile[r][seg * 16 + k * 4 + 2] = v.z;
    tile[r][seg * 16 + k * 4 + 3] = v.w;
    s  += v.x + v.y + v.z + v.w;
    ss += v.x * v.x + v.y * v.y + v.z * v.z + v.w * v.w;
  }
  #pragma unroll
  for (int d = 1; d < 8; d <<= 1) {
    s  += __shfl_xor(s, d, 8);
    ss += __shfl_xor(ss, d, 8);
  }
  float st = 0.0f;
  if (seg == 0) {
    float var = (ss - s * s * (1.0f / 128.0f)) * (1.0f / 127.0f);  // ddof=1
    st = 1.0f / (var + 1e-6f);
    stab[(size_t)b * SEQ + j0 + r] = st;
  }
  float m = st;
  #pragma unroll
  for (int d = 1; d < 64; d <<= 1) m = fmaxf(m, __shfl_xor(m, d, 64));
  if ((t & 63) == 0) wmax[t >> 6] = m;
  __syncthreads();
  if (t == 0) {
    float mm = fmaxf(fmaxf(wmax[0], wmax[1]), fmaxf(wmax[2], wmax[3]));
    atomicMax(gmax, __float_as_uint(mm));   // positive floats: uint order == float order
  }
  // transposed bf16 write: thread t -> f = t>>1, j-half = t&1
  int f  = t >> 1;
  int jh = t & 1;
  unsigned short obuf[16];
  #pragma unroll
  for (int jj = 0; jj < 16; jj++) obuf[jj] = f2bf(tile[jh * 16 + jj][f]);
  unsigned short* dst = featT + ((size_t)(b * FEATD + f)) * SEQ + j0 + jh * 16;
  *(uint4*)(dst)     = *(const uint4*)&obuf[0];
  *(uint4*)(dst + 8) = *(const uint4*)&obuf[8];
}

// ---------------- kernel 2: split-K fused exp + (e @ featT) partial ----------------
#define LOADN4(JTV, N0, N1, N2, N3) { \
    const float4* p_ = (const float4*)(nbase + (size_t)(JTV) * JT); \
    N0 = p_[0]; N1 = p_[1]; N2 = p_[8]; N3 = p_[9]; }

#define PROCB(N0, N1, N2, N3, PK0, PK1) { \
    float x_[16] = {N0.x, N0.y, N0.z, N0.w, N1.x, N1.y, N1.z, N1.w, \
                    N2.x, N2.y, N2.z, N2.w, N3.x, N3.y, N3.z, N3.w}; \
    _Pragma("unroll") \
    for (int k_ = 0; k_ < 8; k_++) { \
      float e_ = __expf(x_[k_] * sn); psum += e_; PK0[k_] = (short)f2bf(e_); } \
    _Pragma("unroll") \
    for (int k_ = 0; k_ < 8; k_++) { \
      float e_ = __expf(x_[8 + k_] * sn); psum += e_; PK1[k_] = (short)f2bf(e_); } }

#define GLLSLOT(JTV, SLOT) { \
    gll16(g0 + (size_t)(JTV) * JT, l0 + (SLOT) * (FEATD * JT)); \
    gll16(g1 + (size_t)(JTV) * JT, l1 + (SLOT) * (FEATD * JT)); \
    gll16(g2 + (size_t)(JTV) * JT, l2 + (SLOT) * (FEATD * JT)); \
    gll16(g3 + (size_t)(JTV) * JT, l3 + (SLOT) * (FEATD * JT)); }

#define DOMFMA(SLOT, PK0, PK1) { \
    _Pragma("unroll") \
    for (int fc = 0; fc < 4; fc++) { \
      const unsigned short* bp_ = &fT[SLOT][wf + fc * 16 + l15][0]; \
      short8 b0_ = *(const short8*)(bp_ + ((lg ^ sw7) << 3)); \
      short8 b1_ = *(const short8*)(bp_ + (((4 | lg) ^ sw7) << 3)); \
      acc[fc] = __builtin_amdgcn_mfma_f32_16x16x32_bf16(PK0, b0_, acc[fc], 0, 0, 0); \
      acc[fc] = __builtin_amdgcn_mfma_f32_16x16x32_bf16(PK1, b1_, acc[fc], 0, 0, 0); \
    } }

__global__ __launch_bounds__(256, 4)
void fused_kernel(const float* __restrict__ noise,
                  const unsigned short* __restrict__ featT,
                  const float* __restrict__ stab,
                  const unsigned int* __restrict__ gmaxp,
                  float* __restrict__ pout,
                  float* __restrict__ psums) {
  // unit-swizzled bf16 B-tile: LDS unit (r*8+s) holds global 16B-unit (s^(r&7)) of row r
  __shared__ unsigned short fT[2][FEATD][JT];   // 32 KB

  int bid  = blockIdx.x;
  int b    = bid >> 7;
  int rest = bid & 127;
  int i0   = (rest >> 1) * IBLK;
  int ks   = rest & 1;
  int jb   = ks * KLEN;

  int t = threadIdx.x;
  int wv = t >> 6, lane = t & 63, l15 = lane & 15, lg = lane >> 4;
  int wi = (wv >> 1) * 16, wf = (wv & 1) * 64;
  int sw7 = l15 & 7;
  int row = i0 + wi + l15;

  float gmaxv = __uint_as_float(*gmaxp);
  float sn = stab[(size_t)b * SEQ + row] / gmaxv;

  const float* nbase = noise + ((size_t)b * SEQ + row) * SEQ + jb + lg * 8;

  // gll: wave wv stages fT 16B-units [256*wv, 256*wv+256), 4 issues of 64 lanes.
  // LDS linear unit idx = 256*wv + 64*m + lane -> row r=idx>>3, swz-slot s=idx&7,
  // global unit u = s^(r&7). Global src is per-lane; LDS dest wave-uniform base.
  unsigned short* lbase = &fT[0][0][0];
  const unsigned short* g0; const unsigned short* g1;
  const unsigned short* g2; const unsigned short* g3;
  unsigned short *l0, *l1, *l2, *l3;
  {
    int i0u = wv * 256 + lane;
    #define GSRC(M) (featT + ((size_t)(b * FEATD + ((i0u + 64*(M)) >> 3))) * SEQ + jb \
                     + ((((i0u + 64*(M)) & 7) ^ (((i0u + 64*(M)) >> 3) & 7)) * 8))
    g0 = GSRC(0); g1 = GSRC(1); g2 = GSRC(2); g3 = GSRC(3);
    #undef GSRC
    l0 = lbase + (wv * 256 + 0)   * 8;
    l1 = lbase + (wv * 256 + 64)  * 8;
    l2 = lbase + (wv * 256 + 128) * 8;
    l3 = lbase + (wv * 256 + 192) * 8;
  }

  f32x4 acc[4];
  #pragma unroll
  for (int k = 0; k < 4; k++) {
    f32x4 z = {0.0f, 0.0f, 0.0f, 0.0f};
    acc[k] = z;
  }
  float psum = 0.0f;

  float4 nA0, nA1, nA2, nA3, nB0, nB1, nB2, nB3;
  short8 pkA0, pkA1, pkB0, pkB1;

  GLLSLOT(0, 0);
  LOADN4(0, nA0, nA1, nA2, nA3);
  __syncthreads();   // drains vmcnt -> fT[0] staged

  for (int jt = 0; jt < NJT; jt += 2) {
    // iter jt: compute from slot0, prefetch fT[jt+1]->slot1
    GLLSLOT(jt + 1, 1);
    LOADN4(jt + 1, nB0, nB1, nB2, nB3);
    PROCB(nA0, nA1, nA2, nA3, pkA0, pkA1);
    DOMFMA(0, pkA0, pkA1);
    __syncthreads();
    // iter jt+1: compute from slot1, prefetch fT[jt+2]->slot0
    if (jt + 2 < NJT) {
      GLLSLOT(jt + 2, 0);
      LOADN4(jt + 2, nA0, nA1, nA2, nA3);
    }
    PROCB(nB0, nB1, nB2, nB3, pkB0, pkB1);
    DOMFMA(1, pkB0, pkB1);
    __syncthreads();
  }

  // row sums: each lane covered cols {lg*8..+8} U {32+lg*8..+8} per jt; reduce over lg
  psum += __shfl_xor(psum, 16, 64);
  psum += __shfl_xor(psum, 32, 64);
  if ((wv & 1) == 0 && lg == 0) {
    psums[(size_t)ks * BATCH * SEQ + (size_t)b * SEQ + i0 + wi + l15] = psum;
  }

  // write f32 partials (no normalize)
  float* orow = pout + (((size_t)(ks * BATCH + b)) * SEQ + i0 + wi) * FEATD + wf;
  #pragma unroll
  for (int v = 0; v < 4; v++) {
    int r = lg * 4 + v;                 // D row = (lane>>4)*4 + reg (m89-verified)
    #pragma unroll
    for (int fc = 0; fc < 4; fc++) {
      orow[(size_t)r * FEATD + fc * 16 + l15] = acc[fc][v];
    }
  }
}

// ---------------- kernel 3: combine partials + normalize ----------------
__global__ __launch_bounds__(256)
void combine_kernel(const float* __restrict__ pout,
                    const float* __restrict__ psums,
                    float* __restrict__ out) {
  int e4 = blockIdx.x * 256 + threadIdx.x;      // float4 index, 0..524287
  int rowg = e4 >> 5;                           // 32 float4 per 128-f row
  const float4* p0 = (const float4*)pout + e4;
  const float4* p1 = p0 + (size_t)BATCH * SEQ * FEATD / 4;
  float s = psums[rowg] + psums[BATCH * SEQ + rowg];
  float rinv = 1.0f / s;
  float4 a = *p0, c = *p1, o;
  o.x = (a.x + c.x) * rinv;
  o.y = (a.y + c.y) * rinv;
  o.z = (a.z + c.z) * rinv;
  o.w = (a.w + c.w) * rinv;
  ((float4*)out)[e4] = o;
}

extern "C" void kernel_launch(void* const* d_in, const int* in_sizes, int n_in,
                              void* d_out, int out_size, void* d_ws, size_t ws_size,
                              hipStream_t stream) {
  const float* feature = (const float*)d_in[0];
  const float* noise   = (const float*)d_in[1];
  float* out = (float*)d_out;

  // ws layout: [0,64K) stab; [64K] gmax; [128K,+4.2M) featT bf16;
  //            [8M,+16.8M) pout f32 x2; [32M,+128K) psums f32 x2
  float* stab           = (float*)d_ws;
  unsigned int* gmax    = (unsigned int*)((char*)d_ws + (64 << 10));
  unsigned short* featT = (unsigned short*)((char*)d_ws + (128 << 10));
  float* pout           = (float*)((char*)d_ws + (8 << 20));
  float* psums          = (float*)((char*)d_ws + (32 << 20));

  hipMemsetAsync(gmax, 0, sizeof(unsigned int), stream);
  prep_kernel<<<dim3(BATCH * SEQ / 32), dim3(256), 0, stream>>>(feature, stab, gmax, featT);
  fused_kernel<<<dim3(BATCH * (SEQ / IBLK) * KSPLIT), dim3(256), 0, stream>>>(
      noise, featT, stab, gmax, pout, psums);
  combine_kernel<<<dim3(BATCH * SEQ * FEATD / 4 / 256), dim3(256), 0, stream>>>(
      pout, psums, out);
}

// Round 6
// 225.955 us; speedup vs baseline: 1.3589x; 1.0117x over previous
//
#include <hip/hip_runtime.h>
#include <hip/hip_bf16.h>

#define BATCH 8
#define SEQ   2048
#define FEATD 128
#define IBLK  32
#define JT    64
#define NJT   (SEQ / JT)   // 32

typedef __attribute__((ext_vector_type(8))) short short8;
typedef __attribute__((ext_vector_type(4))) float f32x4;

__device__ __forceinline__ unsigned short f2bf(float f) {
  unsigned int u = __float_as_uint(f);
  u += 0x7fffu + ((u >> 16) & 1u);   // round-to-nearest-even
  return (unsigned short)(u >> 16);
}

__device__ __forceinline__ void gll16(const unsigned short* gsrc, unsigned short* lds) {
  __builtin_amdgcn_global_load_lds(
      (const __attribute__((address_space(1))) void*)gsrc,
      (__attribute__((address_space(3))) void*)lds, 16, 0, 0);
}

// ---------------- kernel 1: stats (var->stab, block-reduced max) + bf16 transpose ----------------
__global__ __launch_bounds__(256)
void prep_kernel(const float* __restrict__ feature,
                 float* __restrict__ stab,
                 unsigned int* __restrict__ gmax,
                 unsigned short* __restrict__ featT) {
  __shared__ float tile[32][133];
  __shared__ float wmax[4];
  int bid = blockIdx.x;
  int b   = bid >> 6;
  int j0  = (bid & 63) * 32;
  int t   = threadIdx.x;
  int r   = t >> 3;      // row 0..31
  int seg = t & 7;       // 8 segs x 16 floats

  const float* rp = feature + ((size_t)(b * SEQ + j0 + r)) * FEATD + seg * 16;
  float s = 0.0f, ss = 0.0f;
  #pragma unroll
  for (int k = 0; k < 4; k++) {
    float4 v = ((const float4*)rp)[k];
    tile[r][seg * 16 + k * 4 + 0] = v.x;
    tile[r][seg * 16 + k * 4 + 1] = v.y;
    tile[r][seg * 16 + k * 4 + 2] = v.z;
    tile[r][seg * 16 + k * 4 + 3] = v.w;
    s  += v.x + v.y + v.z + v.w;
    ss += v.x * v.x + v.y * v.y + v.z * v.z + v.w * v.w;
  }
  #pragma unroll
  for (int d = 1; d < 8; d <<= 1) {
    s  += __shfl_xor(s, d, 8);
    ss += __shfl_xor(ss, d, 8);
  }
  float st = 0.0f;
  if (seg == 0) {
    float var = (ss - s * s * (1.0f / 128.0f)) * (1.0f / 127.0f);  // ddof=1
    st = 1.0f / (var + 1e-6f);
    stab[(size_t)b * SEQ + j0 + r] = st;
  }
  float m = st;
  #pragma unroll
  for (int d = 1; d < 64; d <<= 1) m = fmaxf(m, __shfl_xor(m, d, 64));
  if ((t & 63) == 0) wmax[t >> 6] = m;
  __syncthreads();
  if (t == 0) {
    float mm = fmaxf(fmaxf(wmax[0], wmax[1]), fmaxf(wmax[2], wmax[3]));
    atomicMax(gmax, __float_as_uint(mm));   // positive floats: uint order == float order
  }
  // transposed bf16 write: thread t -> f = t>>1, j-half = t&1
  int f  = t >> 1;
  int jh = t & 1;
  unsigned short obuf[16];
  #pragma unroll
  for (int jj = 0; jj < 16; jj++) obuf[jj] = f2bf(tile[jh * 16 + jj][f]);
  unsigned short* dst = featT + ((size_t)(b * FEATD + f)) * SEQ + j0 + jh * 16;
  *(uint4*)(dst)     = *(const uint4*)&obuf[0];
  *(uint4*)(dst + 8) = *(const uint4*)&obuf[8];
}

// ---------------- kernel 2: fused exp + (e @ featT) + normalize ----------------
#define LOADN4(JTV, N0, N1, N2, N3) { \
    const float4* p_ = (const float4*)(nbase + (size_t)(JTV) * JT); \
    N0 = p_[0]; N1 = p_[1]; N2 = p_[8]; N3 = p_[9]; }

#define PROCB(N0, N1, N2, N3, PK0, PK1) { \
    float x_[16] = {N0.x, N0.y, N0.z, N0.w, N1.x, N1.y, N1.z, N1.w, \
                    N2.x, N2.y, N2.z, N2.w, N3.x, N3.y, N3.z, N3.w}; \
    _Pragma("unroll") \
    for (int k_ = 0; k_ < 8; k_++) { \
      float e_ = __expf(x_[k_] * sn); psum += e_; PK0[k_] = (short)f2bf(e_); } \
    _Pragma("unroll") \
    for (int k_ = 0; k_ < 8; k_++) { \
      float e_ = __expf(x_[8 + k_] * sn); psum += e_; PK1[k_] = (short)f2bf(e_); } }

#define GLLSLOT(JTV, SLOT) { \
    gll16(g0 + (size_t)(JTV) * JT, l0 + (SLOT) * (FEATD * JT)); \
    gll16(g1 + (size_t)(JTV) * JT, l1 + (SLOT) * (FEATD * JT)); \
    gll16(g2 + (size_t)(JTV) * JT, l2 + (SLOT) * (FEATD * JT)); \
    gll16(g3 + (size_t)(JTV) * JT, l3 + (SLOT) * (FEATD * JT)); }

#define DOMFMA(SLOT, PK0, PK1) { \
    _Pragma("unroll") \
    for (int fc = 0; fc < 4; fc++) { \
      const unsigned short* bp_ = &fT[SLOT][wf + fc * 16 + l15][0]; \
      short8 b0_ = *(const short8*)(bp_ + ((lg ^ sw7) << 3)); \
      short8 b1_ = *(const short8*)(bp_ + (((4 | lg) ^ sw7) << 3)); \
      acc[fc] = __builtin_amdgcn_mfma_f32_16x16x32_bf16(PK0, b0_, acc[fc], 0, 0, 0); \
      acc[fc] = __builtin_amdgcn_mfma_f32_16x16x32_bf16(PK1, b1_, acc[fc], 0, 0, 0); \
    } }

// counted-vmcnt barrier (T4): keep the 4 newest loads (next-tile noise) in flight;
// retire this wave's older GLLs (the slot all waves are about to read), then rendezvous.
#define VBAR(N) { \
    asm volatile("s_waitcnt vmcnt(" #N ")" ::: "memory"); \
    __builtin_amdgcn_s_barrier(); \
    asm volatile("" ::: "memory"); \
    __builtin_amdgcn_sched_barrier(0); }

__global__ __launch_bounds__(256, 4)
void fused_kernel(const float* __restrict__ noise,
                  const unsigned short* __restrict__ featT,
                  const float* __restrict__ stab,
                  const unsigned int* __restrict__ gmaxp,
                  float* __restrict__ out) {
  // unit-swizzled bf16 B-tile: LDS unit (r*8+s) holds global 16B-unit (s^(r&7)) of row r
  __shared__ unsigned short fT[2][FEATD][JT];   // 32 KB -> 4 blocks/CU

  int bid = blockIdx.x;
  int b   = bid >> 6;
  int i0  = (bid & 63) * IBLK;

  int t = threadIdx.x;
  int wv = t >> 6, lane = t & 63, l15 = lane & 15, lg = lane >> 4;
  int wi = (wv >> 1) * 16, wf = (wv & 1) * 64;
  int sw7 = l15 & 7;
  int row = i0 + wi + l15;

  float gmaxv = __uint_as_float(*gmaxp);
  float sn = stab[(size_t)b * SEQ + row] / gmaxv;

  const float* nbase = noise + ((size_t)b * SEQ + row) * SEQ + lg * 8;

  // gll: wave wv stages fT 16B-units [256*wv, 256*wv+256), 4 issues of 64 lanes.
  // LDS linear unit idx -> row r=idx>>3, swz slot s=idx&7, global unit u=s^(r&7).
  unsigned short* lbase = &fT[0][0][0];
  const unsigned short* g0; const unsigned short* g1;
  const unsigned short* g2; const unsigned short* g3;
  unsigned short *l0, *l1, *l2, *l3;
  {
    int i0u = wv * 256 + lane;
    #define GSRC(M) (featT + ((size_t)(b * FEATD + ((i0u + 64*(M)) >> 3))) * SEQ \
                     + ((((i0u + 64*(M)) & 7) ^ (((i0u + 64*(M)) >> 3) & 7)) * 8))
    g0 = GSRC(0); g1 = GSRC(1); g2 = GSRC(2); g3 = GSRC(3);
    #undef GSRC
    l0 = lbase + (wv * 256 + 0)   * 8;
    l1 = lbase + (wv * 256 + 64)  * 8;
    l2 = lbase + (wv * 256 + 128) * 8;
    l3 = lbase + (wv * 256 + 192) * 8;
  }

  f32x4 acc[4];
  #pragma unroll
  for (int k = 0; k < 4; k++) {
    f32x4 z = {0.0f, 0.0f, 0.0f, 0.0f};
    acc[k] = z;
  }
  float psum = 0.0f;

  float4 nA0, nA1, nA2, nA3, nB0, nB1, nB2, nB3;
  short8 pkA0, pkA1, pkB0, pkB1;

  GLLSLOT(0, 0);
  LOADN4(0, nA0, nA1, nA2, nA3);

  // steady state (tiles 0 .. NJT-3): uniform body, counted waits only.
  // vmcnt ledger per wave at each VBAR: 4 newest (next-tile noise) stay in flight;
  // the GLLs for the slot being handed to DOMFMA are retired.
  for (int jt = 0; jt < NJT - 2; jt += 2) {
    LOADN4(jt + 1, nB0, nB1, nB2, nB3);
    PROCB(nA0, nA1, nA2, nA3, pkA0, pkA1);
    VBAR(4);                   // slot0 GLLs landed chip-wide; nB stays in flight
    GLLSLOT(jt + 1, 1);
    DOMFMA(0, pkA0, pkA1);
    LOADN4(jt + 2, nA0, nA1, nA2, nA3);
    PROCB(nB0, nB1, nB2, nB3, pkB0, pkB1);
    VBAR(4);                   // slot1 GLLs landed; nA stays in flight
    GLLSLOT(jt + 2, 0);
    DOMFMA(1, pkB0, pkB1);
  }

  // peeled final pair (tiles NJT-2, NJT-1): no further prefetch, so the last
  // barrier needs a FULL drain (R5 bug: vmcnt(4) was a no-op here -> race).
  LOADN4(NJT - 1, nB0, nB1, nB2, nB3);
  PROCB(nA0, nA1, nA2, nA3, pkA0, pkA1);
  VBAR(4);
  GLLSLOT(NJT - 1, 1);
  DOMFMA(0, pkA0, pkA1);
  PROCB(nB0, nB1, nB2, nB3, pkB0, pkB1);
  VBAR(0);                     // drain: slot1 GLLs definitely landed
  DOMFMA(1, pkB0, pkB1);

  // row sums: reduce the 4 lg-lane copies of each row
  psum += __shfl_xor(psum, 16, 64);
  psum += __shfl_xor(psum, 32, 64);
  // lane with l15=r now holds rowsum(row wi+r)

  float* orow = out + ((size_t)b * SEQ + i0 + wi) * FEATD + wf;
  #pragma unroll
  for (int v = 0; v < 4; v++) {
    int r = lg * 4 + v;                  // D row = (lane>>4)*4 + reg (m89-verified)
    float rs = __shfl(psum, r, 64);
    float rinv = 1.0f / rs;
    #pragma unroll
    for (int fc = 0; fc < 4; fc++) {
      orow[(size_t)r * FEATD + fc * 16 + l15] = acc[fc][v] * rinv;
    }
  }
}

extern "C" void kernel_launch(void* const* d_in, const int* in_sizes, int n_in,
                              void* d_out, int out_size, void* d_ws, size_t ws_size,
                              hipStream_t stream) {
  const float* feature = (const float*)d_in[0];
  const float* noise   = (const float*)d_in[1];
  float* out = (float*)d_out;

  // ws layout: [0,64K) stab f32[16384]; [64K] gmax u32; [128K,+4.2M) featT bf16
  float* stab           = (float*)d_ws;
  unsigned int* gmax    = (unsigned int*)((char*)d_ws + (64 << 10));
  unsigned short* featT = (unsigned short*)((char*)d_ws + (128 << 10));

  hipMemsetAsync(gmax, 0, sizeof(unsigned int), stream);
  prep_kernel<<<dim3(BATCH * SEQ / 32), dim3(256), 0, stream>>>(feature, stab, gmax, featT);
  fused_kernel<<<dim3(BATCH * SEQ / IBLK), dim3(256), 0, stream>>>(noise, featT, stab, gmax, out);
}